// Round 10
// baseline (607.419 us; speedup 1.0000x reference)
//
#include <hip/hip_runtime.h>

typedef float f32x4 __attribute__((ext_vector_type(4)));
typedef _Float16 f16x8 __attribute__((ext_vector_type(8)));
typedef __fp16 fp16x2 __attribute__((ext_vector_type(2)));   // cvt_pkrtz return type

#define M_TOT 16384
#define K_IN  4096
#define R_DIM 128
#define N_OUT 4096

__device__ __forceinline__ _Float16 sign_f16(float v) {
  return v > 0.f ? (_Float16)1.f : (v < 0.f ? (_Float16)-1.f : (_Float16)0.f);
}

// f32x4 pair -> f16 hi + f16 lo (pair sum accurate to ~2^-21 rel)
__device__ __forceinline__ void cvt8v(f32x4 a, f32x4 b, f16x8& h, f16x8& l) {
#pragma unroll
  for (int j = 0; j < 2; ++j) {
    fp16x2 h0 = __builtin_amdgcn_cvt_pkrtz(a[2 * j], a[2 * j + 1]);
    fp16x2 h1 = __builtin_amdgcn_cvt_pkrtz(b[2 * j], b[2 * j + 1]);
    fp16x2 l0 = __builtin_amdgcn_cvt_pkrtz(a[2 * j] - (float)h0[0], a[2 * j + 1] - (float)h0[1]);
    fp16x2 l1 = __builtin_amdgcn_cvt_pkrtz(b[2 * j] - (float)h1[0], b[2 * j + 1] - (float)h1[1]);
    h[2 * j] = (_Float16)h0[0]; h[2 * j + 1] = (_Float16)h0[1];
    h[4 + 2 * j] = (_Float16)h1[0]; h[5 + 2 * j] = (_Float16)h1[1];
    l[2 * j] = (_Float16)l0[0]; l[2 * j + 1] = (_Float16)l0[1];
    l[4 + 2 * j] = (_Float16)l1[0]; l[5 + 2 * j] = (_Float16)l1[1];
  }
}

__device__ __forceinline__ void gload16(const void* g, void* l) {
  __builtin_amdgcn_global_load_lds((const __attribute__((address_space(1))) unsigned int*)g,
                                   (__attribute__((address_space(3))) unsigned int*)l, 16, 0, 0);
}

// ---------------- prep (unchanged from R9) ---------------------------------
__global__ __launch_bounds__(256)
void k_prep(const float* __restrict__ U, const float* __restrict__ V,
            _Float16* __restrict__ VsT_sw, _Float16* __restrict__ Us) {
  __shared__ _Float16 tl[128 * 72];
  const int t = threadIdx.x;
  const int b = blockIdx.x;          // 0..255

  {
    size_t base = (size_t)b * 2048 + (size_t)t * 8;
    f32x4 u0 = *(const f32x4*)(U + base);
    f32x4 u1 = *(const f32x4*)(U + base + 4);
    f16x8 s;
#pragma unroll
    for (int j = 0; j < 4; ++j) { s[j] = sign_f16(u0[j]); s[j + 4] = sign_f16(u1[j]); }
    *(f16x8*)(Us + base) = s;
  }

  if (b < 64) {                      // V tile: k in [64b, 64b+64)
#pragma unroll
    for (int it = 0; it < 8; ++it) {
      int idx4 = it * 256 + t;       // 0..2047
      int kl = idx4 >> 5;            // 0..63
      int r4 = (idx4 & 31) * 4;
      f32x4 v = *(const f32x4*)(V + (size_t)(b * 64 + kl) * R_DIM + r4);
#pragma unroll
      for (int j = 0; j < 4; ++j) tl[(r4 + j) * 72 + kl] = sign_f16(v[j]);
    }
    __syncthreads();
#pragma unroll
    for (int c = 0; c < 4; ++c) {
      int off = t * 64 + c * 16;     // byte offset in 16KB tile
      int r = off >> 7;
      int cB = (off & 127) ^ ((r & 7) << 4);
      f16x8 o = *(const f16x8*)(tl + r * 72 + (cB >> 1));
      *(f16x8*)((char*)VsT_sw + (size_t)b * 16384 + off) = o;
    }
  }
}

// ---------------- kernel 1 (REBUILT): direct-A, 8 waves, B-only LDS --------
// BM=32, BK=64, 512 thr (8 waves: 2 wr x 4 wc), grid 512 (2 blocks/CU).
// A read direct from global in MFMA lane layout, cvt in regs (2-deep reg dbuf).
// B via gload_lds from pre-swizzled VsT, LDS dbuf 2x16KB.
#define LOADX(T, X0, X1, X2, X3, S0, S1, S2, S3)            \
  {                                                          \
    X0 = *(const f32x4*)(xp + (T) * 64);                     \
    X1 = *(const f32x4*)(xp + (T) * 64 + 4);                 \
    X2 = *(const f32x4*)(xp + (T) * 64 + 32);                \
    X3 = *(const f32x4*)(xp + (T) * 64 + 36);                \
    S0 = *(const f32x4*)(sp + (T) * 64);                     \
    S1 = *(const f32x4*)(sp + (T) * 64 + 4);                 \
    S2 = *(const f32x4*)(sp + (T) * 64 + 32);                \
    S3 = *(const f32x4*)(sp + (T) * 64 + 36);                \
  }

#define K1BODY(T, X0, X1, X2, X3, S0, S1, S2, S3, Y0, Y1, Y2, Y3, R0, R1, R2, R3) \
  {                                                                                \
    f16x8 ah0, al0, ah1, al1;                                                      \
    cvt8v(X0 * S0, X1 * S1, ah0, al0);                                             \
    cvt8v(X2 * S2, X3 * S3, ah1, al1);                                             \
    if ((T) < 63) {                                                                \
      const char* src = (const char*)VsT_sw + (size_t)((T) + 1) * 16384 +          \
                        wave * 1024 + lane * 16;                                   \
      char* dst = smem + (((T) + 1) & 1) * 16384 + wave * 1024;                    \
      gload16(src, dst);                                                           \
      gload16(src + 8192, dst + 8192);                                             \
      LOADX((T) + 1, Y0, Y1, Y2, Y3, R0, R1, R2, R3);                              \
    }                                                                              \
    const char* bb = smem + ((T) & 1) * 16384;                                     \
    f16x8 b00 = *(const f16x8*)(bb + brow0 * 128 + ((kq16) ^ bsw0));               \
    f16x8 b01 = *(const f16x8*)(bb + brow0 * 128 + ((64 + kq16) ^ bsw0));          \
    f16x8 b10 = *(const f16x8*)(bb + brow1 * 128 + ((kq16) ^ bsw1));               \
    f16x8 b11 = *(const f16x8*)(bb + brow1 * 128 + ((64 + kq16) ^ bsw1));          \
    acc0 = __builtin_amdgcn_mfma_f32_16x16x32_f16(ah0, b00, acc0, 0, 0, 0);        \
    acc0 = __builtin_amdgcn_mfma_f32_16x16x32_f16(al0, b00, acc0, 0, 0, 0);        \
    acc0 = __builtin_amdgcn_mfma_f32_16x16x32_f16(ah1, b01, acc0, 0, 0, 0);        \
    acc0 = __builtin_amdgcn_mfma_f32_16x16x32_f16(al1, b01, acc0, 0, 0, 0);        \
    acc1 = __builtin_amdgcn_mfma_f32_16x16x32_f16(ah0, b10, acc1, 0, 0, 0);        \
    acc1 = __builtin_amdgcn_mfma_f32_16x16x32_f16(al0, b10, acc1, 0, 0, 0);        \
    acc1 = __builtin_amdgcn_mfma_f32_16x16x32_f16(ah1, b11, acc1, 0, 0, 0);        \
    acc1 = __builtin_amdgcn_mfma_f32_16x16x32_f16(al1, b11, acc1, 0, 0, 0);        \
    __syncthreads();                                                               \
  }

__global__ __launch_bounds__(512, 4)
void k1_z(const float* __restrict__ x, const float* __restrict__ s2,
          const _Float16* __restrict__ VsT_sw,
          _Float16* __restrict__ Zswh, _Float16* __restrict__ Zswl) {
  __shared__ char smem[32768];               // B0 @0, B1 @16K; epilogue reuses as ZT
  const int t = threadIdx.x;
  const int lane = t & 63;
  const int wave = t >> 6;
  const int m0 = blockIdx.x * 32;
  const int wr = wave & 1, wc = wave >> 1;   // wc 0..3

  const int kq8 = (lane >> 4) * 8;           // f32 offset of lane's 8-k group
  const int kq16 = (lane >> 4) * 16;         // byte offset in f16
  const int arow = m0 + wr * 16 + (lane & 15);
  const float* xp = x + (size_t)arow * K_IN + kq8;
  const float* sp = s2 + kq8;

  const int brow0 = wc * 32 + (lane & 15);
  const int brow1 = brow0 + 16;
  const int bsw0 = (brow0 & 7) << 4;
  const int bsw1 = (brow1 & 7) << 4;

  f32x4 acc0 = {0.f, 0.f, 0.f, 0.f};
  f32x4 acc1 = {0.f, 0.f, 0.f, 0.f};

  // prologue: stage B tile 0, load x/s2 for t=0
  {
    const char* src = (const char*)VsT_sw + wave * 1024 + lane * 16;
    char* dst = smem + wave * 1024;
    gload16(src, dst);
    gload16(src + 8192, dst + 8192);
  }
  f32x4 xa0, xa1, xa2, xa3, sa0, sa1, sa2, sa3;
  f32x4 xb0, xb1, xb2, xb3, sb0, sb1, sb2, sb3;
  LOADX(0, xa0, xa1, xa2, xa3, sa0, sa1, sa2, sa3);
  __syncthreads();

  for (int tt = 0; tt < 32; ++tt) {
    const int t0 = tt * 2;
    K1BODY(t0,     xa0, xa1, xa2, xa3, sa0, sa1, sa2, sa3,
                   xb0, xb1, xb2, xb3, sb0, sb1, sb2, sb3);
    K1BODY(t0 + 1, xb0, xb1, xb2, xb3, sb0, sb1, sb2, sb3,
                   xa0, xa1, xa2, xa3, sa0, sa1, sa2, sa3);
  }

  // epilogue: shuffle via LDS (reuse smem), convert once, write pre-swizzled Z
  float* ZT = (float*)smem;                  // 32 x 132 f32 = 16.9 KB
#pragma unroll
  for (int j = 0; j < 4; ++j) {
    ZT[(wr * 16 + (lane >> 4) * 4 + j) * 132 + wc * 32 + (lane & 15)]      = acc0[j];
    ZT[(wr * 16 + (lane >> 4) * 4 + j) * 132 + wc * 32 + 16 + (lane & 15)] = acc1[j];
  }
  __syncthreads();
  {
    const int lr = t >> 4;                   // 0..31
    const int c0 = (t & 15) * 8;             // f32 col base
    f32x4 v0 = *(const f32x4*)(ZT + lr * 132 + c0);
    f32x4 v1 = *(const f32x4*)(ZT + lr * 132 + c0 + 4);
    f16x8 h, l;
    cvt8v(v0, v1, h, l);
    const int sw = (lr & 7) << 4;
    const int m = m0 + lr;
    *(f16x8*)((char*)Zswh + (size_t)m * 256 + ((c0 * 2) ^ sw)) = h;
    *(f16x8*)((char*)Zswl + (size_t)m * 256 + ((c0 * 2) ^ sw)) = l;
  }
}

// ---------------- kernel 2 (unchanged from R9) -----------------------------
__global__ __launch_bounds__(256, 4)
void k2_out(const _Float16* __restrict__ Zswh, const _Float16* __restrict__ Zswl,
            const _Float16* __restrict__ Us, const float* __restrict__ s1,
            const float* __restrict__ bias, float* __restrict__ out) {
  __shared__ char smem[32768];              // Zh 16K @0, Zl 16K @16K
  const int t = threadIdx.x;
  const int lane = t & 63;
  const int wave = t >> 6;
  const int bid = blockIdx.x;
  const int nb = bid & 31;                  // nb-fast: 32 blocks share a Z chunk
  const int mb = bid >> 5;
  const int m0 = mb * 64, n0 = nb * 128;
  const int wm = wave & 1, wn = wave >> 1;  // 32-row half x 64-col half

  f16x8 bf[4][4];
#pragma unroll
  for (int ks = 0; ks < 4; ++ks)
#pragma unroll
    for (int nf = 0; nf < 4; ++nf) {
      const int n = n0 + wn * 64 + nf * 16 + (lane & 15);
      bf[ks][nf] = *(const f16x8*)(Us + (size_t)n * R_DIM + ks * 32 + (lane >> 4) * 8);
    }

  const char* gh = (const char*)Zswh + (size_t)m0 * 256;
  const char* gl = (const char*)Zswl + (size_t)m0 * 256;
#pragma unroll
  for (int q = 0; q < 4; ++q) {
    gload16(gh + wave * 1024 + q * 4096 + lane * 16, smem + wave * 1024 + q * 4096);
    gload16(gl + wave * 1024 + q * 4096 + lane * 16, smem + 16384 + wave * 1024 + q * 4096);
  }
  __syncthreads();

  f32x4 acc[2][4] = {};
  const int kq = (lane >> 4) * 16;          // byte
#pragma unroll
  for (int mf = 0; mf < 2; ++mf) {
    const int lr = wm * 32 + mf * 16 + (lane & 15);
    const int sw = (lr & 7) << 4;
#pragma unroll
    for (int ks = 0; ks < 4; ++ks) {
      const int cb = (ks * 64 + kq) ^ sw;
      f16x8 ah = *(const f16x8*)(smem + lr * 256 + cb);
      f16x8 al = *(const f16x8*)(smem + 16384 + lr * 256 + cb);
#pragma unroll
      for (int nf = 0; nf < 4; ++nf) {
        acc[mf][nf] = __builtin_amdgcn_mfma_f32_16x16x32_f16(ah, bf[ks][nf], acc[mf][nf], 0, 0, 0);
        acc[mf][nf] = __builtin_amdgcn_mfma_f32_16x16x32_f16(al, bf[ks][nf], acc[mf][nf], 0, 0, 0);
      }
    }
  }

#pragma unroll
  for (int nf = 0; nf < 4; ++nf) {
    const int col = n0 + wn * 64 + nf * 16 + (lane & 15);
    const float sv = s1[col];
    const float bv = bias[col];
#pragma unroll
    for (int mf = 0; mf < 2; ++mf) {
      const int row = m0 + wm * 32 + mf * 16 + (lane >> 4) * 4;
#pragma unroll
      for (int j = 0; j < 4; ++j)
        out[(size_t)(row + j) * N_OUT + col] = acc[mf][nf][j] * sv + bv;
    }
  }
}

extern "C" void kernel_launch(void* const* d_in, const int* in_sizes, int n_in,
                              void* d_out, int out_size, void* d_ws, size_t ws_size,
                              hipStream_t stream) {
  const float* x    = (const float*)d_in[0];
  const float* U    = (const float*)d_in[1];
  const float* V    = (const float*)d_in[2];
  const float* s1   = (const float*)d_in[3];
  const float* s2   = (const float*)d_in[4];
  const float* bias = (const float*)d_in[5];
  float* out = (float*)d_out;

  // ws: VsT_sw 1MB | Us 1MB | Zswh 4MB | Zswl 4MB
  char* w = (char*)d_ws;
  _Float16* VsT_sw = (_Float16*)(w);
  _Float16* Us     = (_Float16*)(w + (1 << 20));
  _Float16* Zswh   = (_Float16*)(w + (2 << 20));
  _Float16* Zswl   = (_Float16*)(w + (6 << 20));

  k_prep<<<dim3(256), dim3(256), 0, stream>>>(U, V, VsT_sw, Us);
  k1_z<<<dim3(512), dim3(512), 0, stream>>>(x, s2, VsT_sw, Zswh, Zswl);
  k2_out<<<dim3(8192), dim3(256), 0, stream>>>(Zswh, Zswl, Us, s1, bias, out);
}